// Round 14
// baseline (44.191 us; speedup 1.0000x reference)
//
#include <hip/hip_runtime.h>
#include <hip/hip_bf16.h>

// LS2T iterated sums (ORDER=3): B=64, T=4096, D=128, F=64, C=6.
// m_c(t,f) = seq[b,t,:]·kernel[c,:,f] + bias[c,f]
// Y1 = sum m0; Y2 = sum m2*cumx(m1); Y3 = sum m5*cumx(m4*cumx(m3))
//
// Round 14: R13 DMA pipeline + 6-components-per-wave (A-read amortized over
// 6 MFMAs, not 3). 4 waves/block (256 thr), each wave owns 16 f-columns and
// computes all 6 c -> LDS-read traffic per chunk halves (64->32 KB).
// Each wave DMAs its 4 rows per chunk (2x global_load_lds_dwordx4, source
// pre-swizzled, dest linear); counted vmcnt(4), ring-4 LDS (32 KB f32),
// no-drain barriers. Lane runs BOTH scan chains (10 regs), one 10-state
// butterfly pair at the end. bfrag 6x4 short8v lives in AGPRs.

#define B_ 64
#define T_ 4096
#define D_ 128
#define F_ 64
#define NC 6
#define TB 512             // t per block
#define TGROUPS (T_ / TB)  // 8
#define CHT 16             // t per chunk
#define NITER (TB / CHT)   // 32
#define TPB 256
#define RING 4

typedef __attribute__((ext_vector_type(8))) short short8v;
typedef __attribute__((ext_vector_type(4))) float f32x4;

__device__ __forceinline__ unsigned short bfb(float x) {
    __hip_bfloat16 h = __float2bfloat16(x);   // RNE (B operand only)
    unsigned short u;
    __builtin_memcpy(&u, &h, 2);
    return u;
}

// barrier WITHOUT vmcnt drain: waits only LDS ops, keeps DMAs in flight
#define BAR() asm volatile("s_waitcnt lgkmcnt(0)\n\ts_barrier" ::: "memory")
#define VW(n) asm volatile("s_waitcnt vmcnt(" #n ")" ::: "memory")

__global__ __launch_bounds__(TPB)
void ls2t_kernel(const float* __restrict__ seq,
                 const float* __restrict__ kern,
                 const float* __restrict__ bias,
                 float* __restrict__ ws)
{
    __shared__ float slds[RING][CHT * D_];   // 4 x 8 KB f32

    const int tid  = threadIdx.x;
    const int tg   = blockIdx.x;
    const int b    = blockIdx.y;
    const int lane = tid & 63;
    const int w    = tid >> 6;     // wave 0..3 -> f-range
    const int fr   = lane & 15;
    const int lg   = lane >> 4;
    const int f    = w * 16 + fr;

    // ---- B fragments in registers (mfma B: col=lane&15=f, k=(lane>>4)*8+j)
    short8v bfrag[NC][4];
    float bc[NC];
    #pragma unroll
    for (int c = 0; c < NC; ++c) {
        bc[c] = bias[c * F_ + f];
        #pragma unroll
        for (int ks = 0; ks < 4; ++ks) {
            const float* kp = kern + ((size_t)c * D_ + ks * 32 + lg * 8) * F_ + f;
            short8v bf;
            #pragma unroll
            for (int j = 0; j < 8; ++j) bf[j] = (short)bfb(kp[(size_t)j * F_]);
            bfrag[c][ks] = bf;
        }
    }

    const float* sbase = seq + ((size_t)b * T_ + (size_t)tg * TB) * D_;

    // ---- DMA staging geometry ----
    // Wave w stages LDS rows {4w .. 4w+3} of each chunk via 2 loads
    // (j=0,1; load j covers rows 4w+2j+(lane>>5)); dest linear
    // (base + lane*16B). Row r of chunk i holds t_local = (r>>2)*128+i*4+(r&3)
    // (lane-group lg reads contiguous t-stripe [lg*128,+128) over 32 chunks).
    // Swizzle (pre-swizzled SOURCE): LDS 16B-unit u of row r holds global
    // unit (u&24) | ((u^r)&7).
    const int u_lane = lane & 31;             // dest 16B unit within row
    const float* gsrc0[2];
    #pragma unroll
    for (int j = 0; j < 2; ++j) {
        const int r  = 4 * w + 2 * j + (lane >> 5);
        const int gu = (u_lane & 24) | ((u_lane ^ r) & 7);
        gsrc0[j] = sbase + ((size_t)(w * 128 + (r & 3))) * D_ + gu * 4;
    }

    auto issue = [&](int i, int bufi) {
        #pragma unroll
        for (int j = 0; j < 2; ++j) {
            const float* src = gsrc0[j] + (size_t)i * 4 * D_;
            void* dst = (void*)&slds[bufi][w * 512 + j * 256];  // 2 rows/load
            __builtin_amdgcn_global_load_lds(
                (const __attribute__((address_space(1))) void*)src,
                (__attribute__((address_space(3))) void*)dst, 16, 0, 0);
        }
    };

    // scan state: both chains per lane
    float a0 = 0.f, s1 = 0.f, s2 = 0.f, q2 = 0.f;
    float su = 0.f, sv = 0.f, sw = 0.f, qvu = 0.f, qwv = 0.f, qwvu = 0.f;

    auto compute = [&](int bufi) {
        const float* L = &slds[bufi][0];
        f32x4 acc[NC];
        #pragma unroll
        for (int c = 0; c < NC; ++c)
            acc[c] = (f32x4){bc[c], bc[c], bc[c], bc[c]};

        #pragma unroll
        for (int ks = 0; ks < 4; ++ks) {
            // lane (fr,lg) reads A[row=fr][d = ks*32+lg*8 .. +8] (f32):
            // 16B-units u0,u0+1 with the store-side swizzle applied
            const int u0 = ks * 8 + lg * 2;
            const int s0 = (u0 & 24) | ((u0 ^ fr) & 7);
            const int s1u = ((u0 + 1) & 24) | (((u0 + 1) ^ fr) & 7);
            float4 fa = *reinterpret_cast<const float4*>(&L[fr * 128 + s0 * 4]);
            float4 fb = *reinterpret_cast<const float4*>(&L[fr * 128 + s1u * 4]);
            uint4 pk;
            pk.x = __builtin_amdgcn_perm(__float_as_uint(fa.y),
                                         __float_as_uint(fa.x), 0x07060302u);
            pk.y = __builtin_amdgcn_perm(__float_as_uint(fa.w),
                                         __float_as_uint(fa.z), 0x07060302u);
            pk.z = __builtin_amdgcn_perm(__float_as_uint(fb.y),
                                         __float_as_uint(fb.x), 0x07060302u);
            pk.w = __builtin_amdgcn_perm(__float_as_uint(fb.w),
                                         __float_as_uint(fb.z), 0x07060302u);
            short8v a = *reinterpret_cast<short8v*>(&pk);
            #pragma unroll
            for (int c = 0; c < NC; ++c)
                acc[c] = __builtin_amdgcn_mfma_f32_16x16x32_bf16(
                    a, bfrag[c][ks], acc[c], 0, 0, 0);
        }

        // lane owns t = tg*512 + lg*128 + i*4 + r  -> chain both in-lane
        #pragma unroll
        for (int r = 0; r < 4; ++r) {
            float m0 = acc[0][r], m1 = acc[1][r], m2 = acc[2][r];
            float m3 = acc[3][r], m4 = acc[4][r], m5 = acc[5][r];
            a0  += m0;
            q2   = fmaf(m2, s1, q2);      // s1 = exclusive cumsum(m1)
            s2  += m2;
            s1  += m1;
            qwvu = fmaf(m5, qvu, qwvu);
            qwv  = fmaf(m5, sv, qwv);
            sw  += m5;
            qvu  = fmaf(m4, su, qvu);
            sv  += m4;
            su  += m3;
        }
    };

    // ---- pipeline: DMA 3 chunks ahead (2 loads each), counted vmcnt ----
    issue(0, 0); issue(1, 1); issue(2, 2);

    #pragma unroll 1
    for (int i = 0; i < NITER - 3; ++i) {
        VW(4);                 // own chunk-i loads landed (4 newer in flight)
        BAR();                 // => all waves' chunk-i rows landed
        issue(i + 3, (i + 3) & 3);   // overwrites buf (i-1)%4: safe post-BAR
        compute(i & 3);
    }
    // tail: chunks 29,30,31 (outstanding loads drain 4 -> 2 -> 0)
    VW(4); BAR(); compute(1);
    VW(2); BAR(); compute(2);
    VW(0); BAR(); compute(3);

    // ---- merge the 4 lane-group stripes (time order: lg ascending) ----
    #pragma unroll
    for (int m = 16; m <= 32; m <<= 1) {
        float oa0 = __shfl_xor(a0, m),   os1 = __shfl_xor(s1, m);
        float os2 = __shfl_xor(s2, m),   oq2 = __shfl_xor(q2, m);
        float osu = __shfl_xor(su, m),   osv = __shfl_xor(sv, m);
        float osw = __shfl_xor(sw, m),   oqvu = __shfl_xor(qvu, m);
        float oqwv = __shfl_xor(qwv, m), oqwvu = __shfl_xor(qwvu, m);
        const bool up = (lane & m) != 0;   // this lane holds the LATER segment
        float Aa0 = up ? oa0 : a0,   Ba0 = up ? a0 : oa0;
        float As1 = up ? os1 : s1,   Bs1 = up ? s1 : os1;
        float As2 = up ? os2 : s2,   Bs2 = up ? s2 : os2;
        float Aq2 = up ? oq2 : q2,   Bq2 = up ? q2 : oq2;
        float Asu = up ? osu : su,   Bsu = up ? su : osu;
        float Asv = up ? osv : sv,   Bsv = up ? sv : osv;
        float Asw = up ? osw : sw,   Bsw = up ? sw : osw;
        float Aqvu = up ? oqvu : qvu,   Bqvu = up ? qvu : oqvu;
        float Aqwv = up ? oqwv : qwv,   Bqwv = up ? qwv : oqwv;
        float Aqwvu = up ? oqwvu : qwvu, Bqwvu = up ? qwvu : oqwvu;
        a0   = Aa0 + Ba0;
        q2   = Aq2 + Bq2 + As1 * Bs2;
        s1   = As1 + Bs1;
        s2   = As2 + Bs2;
        qwvu = Aqwvu + Bqwvu + Aqvu * Bsw + Asu * Bqwv;
        qwv  = Aqwv + Bqwv + Asv * Bsw;
        qvu  = Aqvu + Bqvu + Asu * Bsv;
        su   = Asu + Bsu;
        sv   = Asv + Bsv;
        sw   = Asw + Bsw;
    }

    if (lg == 0) {
        float* wp = ws + (((size_t)b * TGROUPS + tg) * F_ + f) * 10;
        wp[0] = a0;  wp[1] = s1;  wp[2] = s2;  wp[3] = q2;
        wp[4] = su;  wp[5] = sv;  wp[6] = sw;
        wp[7] = qvu; wp[8] = qwv; wp[9] = qwvu;
    }
}

struct St { float a0, s1, s2, q2, su, sv, sw, qvu, qwv, qwvu; };

__device__ __forceinline__ St mergeSt(const St& A, const St& B) {
    St r;
    r.a0   = A.a0 + B.a0;
    r.q2   = A.q2 + B.q2 + A.s1 * B.s2;
    r.s1   = A.s1 + B.s1;
    r.s2   = A.s2 + B.s2;
    r.qwvu = A.qwvu + B.qwvu + A.qvu * B.sw + A.su * B.qwv;
    r.qwv  = A.qwv + B.qwv + A.sv * B.sw;
    r.qvu  = A.qvu + B.qvu + A.su * B.sv;
    r.su   = A.su + B.su;
    r.sv   = A.sv + B.sv;
    r.sw   = A.sw + B.sw;
    return r;
}

__global__ __launch_bounds__(64)
void ls2t_fold_kernel(const float* __restrict__ ws, float* __restrict__ out)
{
    const int b = blockIdx.x;
    const int f = threadIdx.x;
    St A = {0, 0, 0, 0, 0, 0, 0, 0, 0, 0};
    #pragma unroll
    for (int g = 0; g < TGROUPS; ++g) {
        const float* rp = ws + (((size_t)b * TGROUPS + g) * F_ + f) * 10;
        St r = {rp[0], rp[1], rp[2], rp[3], rp[4],
                rp[5], rp[6], rp[7], rp[8], rp[9]};
        A = mergeSt(A, r);
    }
    float* op = out + ((size_t)b * F_ + f) * 3;
    op[0] = A.a0;
    op[1] = A.q2;
    op[2] = A.qwvu;
}

extern "C" void kernel_launch(void* const* d_in, const int* in_sizes, int n_in,
                              void* d_out, int out_size, void* d_ws, size_t ws_size,
                              hipStream_t stream) {
    const float* seq  = (const float*)d_in[0];
    const float* kern = (const float*)d_in[1];
    const float* bias = (const float*)d_in[2];
    float* out = (float*)d_out;
    float* ws  = (float*)d_ws;   // B_*TGROUPS*F_*10*4 = 1.31 MB

    dim3 g1(TGROUPS, B_);        // 512 blocks x 256 thr
    ls2t_kernel<<<g1, TPB, 0, stream>>>(seq, kern, bias, ws);
    ls2t_fold_kernel<<<B_, F_, 0, stream>>>(ws, out);
}

// Round 15
// 41.077 us; speedup vs baseline: 1.0758x; 1.0758x over previous
//
#include <hip/hip_runtime.h>
#include <hip/hip_bf16.h>

// LS2T iterated sums (ORDER=3): B=64, T=4096, D=128, F=64, C=6.
// m_c(t,f) = seq[b,t,:]·kernel[c,:,f] + bias[c,f]
// Y1 = sum m0; Y2 = sum m2*cumx(m1); Y3 = sum m5*cumx(m4*cumx(m3))
//
// Round 15: R13 (best) with ONE variable: CHT 16->32. Chunk = two 16x16
// MFMA sub-tiles; 16 barrier phases/block (was 32); ring-4 x 16 KB = 64 KB;
// 2 DMA loads/wave/chunk, vmcnt(4) keeps 2 chunks (32 KB/block) in flight.
// DMA staging makes the widening register-free (R11's failure mode gone).
// cg-split waves, B-frags in AGPRs, unified 6-reg scan, butterfly at end.

#define B_ 64
#define T_ 4096
#define D_ 128
#define F_ 64
#define TB 512             // t per block
#define TGROUPS (T_ / TB)  // 8
#define CHT 32             // t per chunk (2 MFMA sub-tiles)
#define NITER (TB / CHT)   // 16
#define TPB 512
#define RING 4

typedef __attribute__((ext_vector_type(8))) short short8v;
typedef __attribute__((ext_vector_type(4))) float f32x4;

__device__ __forceinline__ unsigned short bfb(float x) {
    __hip_bfloat16 h = __float2bfloat16(x);   // RNE (B operand only)
    unsigned short u;
    __builtin_memcpy(&u, &h, 2);
    return u;
}

// barrier WITHOUT vmcnt drain: waits only LDS ops, keeps DMAs in flight
#define BAR() asm volatile("s_waitcnt lgkmcnt(0)\n\ts_barrier" ::: "memory")
#define VW(n) asm volatile("s_waitcnt vmcnt(" #n ")" ::: "memory")

__global__ __launch_bounds__(TPB)
void ls2t_kernel(const float* __restrict__ seq,
                 const float* __restrict__ kern,
                 const float* __restrict__ bias,
                 float* __restrict__ ws)
{
    __shared__ float slds[RING][CHT * D_];   // 4 x 16 KB f32

    const int tid  = threadIdx.x;
    const int tg   = blockIdx.x;
    const int b    = blockIdx.y;
    const int lane = tid & 63;
    const int w    = tid >> 6;
    const int cg   = w >> 2;       // 0 -> c0..2 (Y1,Y2), 1 -> c3..5 (Y3)
    const int wv   = w & 3;        // f-range of this wave
    const int fr   = lane & 15;
    const int lg   = lane >> 4;
    const int f    = wv * 16 + fr;

    // ---- B fragments in registers (mfma B: col=lane&15=f, k=(lane>>4)*8+j)
    short8v bfrag[3][4];
    float bc[3];
    #pragma unroll
    for (int cc = 0; cc < 3; ++cc) {
        const int c = cg * 3 + cc;
        bc[cc] = bias[c * F_ + f];
        #pragma unroll
        for (int ks = 0; ks < 4; ++ks) {
            const float* kp = kern + ((size_t)c * D_ + ks * 32 + lg * 8) * F_ + f;
            short8v bf;
            #pragma unroll
            for (int j = 0; j < 8; ++j) bf[j] = (short)bfb(kp[(size_t)j * F_]);
            bfrag[cc][ks] = bf;
        }
    }

    const float* sbase = seq + ((size_t)b * T_ + (size_t)tg * TB) * D_;

    // ---- DMA staging geometry ----
    // Chunk = 32 rows. Row R (0..31) of chunk i holds
    //   t_local = ((R&15)>>2)*128 + ((R>>4)<<2) + (R&3) + i*8
    // (sub-tile tf=R>>4, MFMA row rho=R&15; lane-group lg owns contiguous
    // t-stripe [lg*128,+128) over the 16 chunks). Wave w stages rows
    // {4w..4w+3} via 2 loads (load j covers rows 4w+2j+(lane>>5)); dest
    // linear (base + lane*16B). Pre-swizzled SOURCE: LDS 16B-unit u of row R
    // holds global unit (u&24) | ((u^R)&7).
    const int u_lane = lane & 31;
    const float* gsrc0[2];
    #pragma unroll
    for (int j = 0; j < 2; ++j) {
        const int r  = 4 * w + 2 * j + (lane >> 5);
        const int gu = (u_lane & 24) | ((u_lane ^ r) & 7);
        const int t0 = ((r & 15) >> 2) * 128 + ((r >> 4) << 2) + (r & 3);
        gsrc0[j] = sbase + (size_t)t0 * D_ + gu * 4;
    }

    auto issue = [&](int i, int bufi) {
        #pragma unroll
        for (int j = 0; j < 2; ++j) {
            const float* src = gsrc0[j] + (size_t)i * 8 * D_;
            void* dst = (void*)&slds[bufi][(4 * w + 2 * j) * 128];
            __builtin_amdgcn_global_load_lds(
                (const __attribute__((address_space(1))) void*)src,
                (__attribute__((address_space(3))) void*)dst, 16, 0, 0);
        }
    };

    // unified scan state (cg0: a0=x0,s1=x1,s2=x2,q2=x4; cg1: su..qwvu=x0..x5)
    float x0 = 0.f, x1 = 0.f, x2 = 0.f, x3 = 0.f, x4 = 0.f, x5 = 0.f;

    auto compute = [&](int bufi) {
        const float* L = &slds[bufi][0];
        #pragma unroll
        for (int tf = 0; tf < 2; ++tf) {       // two 16x16 sub-tiles
            f32x4 acc[3];
            #pragma unroll
            for (int cc = 0; cc < 3; ++cc)
                acc[cc] = (f32x4){bc[cc], bc[cc], bc[cc], bc[cc]};

            const int rowbase = (tf * 16 + fr) * 128;
            #pragma unroll
            for (int ks = 0; ks < 4; ++ks) {
                const int u0  = ks * 8 + lg * 2;
                const int s0  = (u0 & 24) | ((u0 ^ fr) & 7);
                const int s1u = ((u0 + 1) & 24) | (((u0 + 1) ^ fr) & 7);
                float4 fa = *reinterpret_cast<const float4*>(&L[rowbase + s0 * 4]);
                float4 fb = *reinterpret_cast<const float4*>(&L[rowbase + s1u * 4]);
                uint4 pk;
                pk.x = __builtin_amdgcn_perm(__float_as_uint(fa.y),
                                             __float_as_uint(fa.x), 0x07060302u);
                pk.y = __builtin_amdgcn_perm(__float_as_uint(fa.w),
                                             __float_as_uint(fa.z), 0x07060302u);
                pk.z = __builtin_amdgcn_perm(__float_as_uint(fb.y),
                                             __float_as_uint(fb.x), 0x07060302u);
                pk.w = __builtin_amdgcn_perm(__float_as_uint(fb.w),
                                             __float_as_uint(fb.z), 0x07060302u);
                short8v a = *reinterpret_cast<short8v*>(&pk);
                #pragma unroll
                for (int cc = 0; cc < 3; ++cc)
                    acc[cc] = __builtin_amdgcn_mfma_f32_16x16x32_bf16(
                        a, bfrag[cc][ks], acc[cc], 0, 0, 0);
            }

            // lane owns t = tg*512 + lg*128 + i*8 + tf*4 + r -> chain in-lane
            #pragma unroll
            for (int r = 0; r < 4; ++r) {
                float p = acc[0][r], q = acc[1][r], rr = acc[2][r];
                x5 = fmaf(rr, x3, x5);   // qwvu += m5*qvu            (cg1)
                x4 = fmaf(rr, x1, x4);   // q2 += m2*s1 / qwv += m5*sv
                x3 = fmaf(q,  x0, x3);   // qvu += m4*su              (cg1)
                x2 += rr;                // s2 / sw
                x1 += q;                 // s1 / sv
                x0 += p;                 // a0 / su
            }
        }
    };

    // ---- pipeline: DMA 3 chunks ahead (2 loads each), counted vmcnt ----
    issue(0, 0); issue(1, 1); issue(2, 2);

    #pragma unroll 1
    for (int i = 0; i < NITER - 3; ++i) {
        VW(4);                 // own chunk-i loads landed (4 newer in flight)
        BAR();                 // => all waves' chunk-i rows landed
        issue(i + 3, (i + 3) & 3);   // overwrites buf (i-1)%4: safe post-BAR
        compute(i & 3);
    }
    // tail: chunks 13,14,15 (outstanding loads drain 4 -> 2 -> 0)
    VW(4); BAR(); compute(1);
    VW(2); BAR(); compute(2);
    VW(0); BAR(); compute(3);

    // ---- merge the 4 lane-group stripes (time order: lg ascending) ----
    #pragma unroll
    for (int m = 16; m <= 32; m <<= 1) {
        float o0 = __shfl_xor(x0, m), o1 = __shfl_xor(x1, m);
        float o2 = __shfl_xor(x2, m), o3 = __shfl_xor(x3, m);
        float o4 = __shfl_xor(x4, m), o5 = __shfl_xor(x5, m);
        const bool up = (lane & m) != 0;   // this lane holds the LATER segment
        float A0 = up ? o0 : x0, B0 = up ? x0 : o0;
        float A1 = up ? o1 : x1, B1 = up ? x1 : o1;
        float A2 = up ? o2 : x2, B2 = up ? x2 : o2;
        float A3 = up ? o3 : x3, B3 = up ? x3 : o3;
        float A4 = up ? o4 : x4, B4 = up ? x4 : o4;
        float A5 = up ? o5 : x5, B5 = up ? x5 : o5;
        x5 = A5 + B5 + A3 * B2 + A0 * B4;
        x4 = A4 + B4 + A1 * B2;
        x3 = A3 + B3 + A0 * B1;
        x2 = A2 + B2;
        x1 = A1 + B1;
        x0 = A0 + B0;
    }

    if (lg == 0) {
        float* wp = ws + (((size_t)b * TGROUPS + tg) * F_ + f) * 10;
        if (cg == 0) {
            wp[0] = x0; wp[1] = x1; wp[2] = x2; wp[3] = x4;
        } else {
            wp[4] = x0; wp[5] = x1; wp[6] = x2;
            wp[7] = x3; wp[8] = x4; wp[9] = x5;
        }
    }
}

struct St { float a0, s1, s2, q2, su, sv, sw, qvu, qwv, qwvu; };

__device__ __forceinline__ St mergeSt(const St& A, const St& B) {
    St r;
    r.a0   = A.a0 + B.a0;
    r.q2   = A.q2 + B.q2 + A.s1 * B.s2;
    r.s1   = A.s1 + B.s1;
    r.s2   = A.s2 + B.s2;
    r.qwvu = A.qwvu + B.qwvu + A.qvu * B.sw + A.su * B.qwv;
    r.qwv  = A.qwv + B.qwv + A.sv * B.sw;
    r.qvu  = A.qvu + B.qvu + A.su * B.sv;
    r.su   = A.su + B.su;
    r.sv   = A.sv + B.sv;
    r.sw   = A.sw + B.sw;
    return r;
}

__global__ __launch_bounds__(64)
void ls2t_fold_kernel(const float* __restrict__ ws, float* __restrict__ out)
{
    const int b = blockIdx.x;
    const int f = threadIdx.x;
    St A = {0, 0, 0, 0, 0, 0, 0, 0, 0, 0};
    #pragma unroll
    for (int g = 0; g < TGROUPS; ++g) {
        const float* rp = ws + (((size_t)b * TGROUPS + g) * F_ + f) * 10;
        St r = {rp[0], rp[1], rp[2], rp[3], rp[4],
                rp[5], rp[6], rp[7], rp[8], rp[9]};
        A = mergeSt(A, r);
    }
    float* op = out + ((size_t)b * F_ + f) * 3;
    op[0] = A.a0;
    op[1] = A.q2;
    op[2] = A.qwvu;
}

extern "C" void kernel_launch(void* const* d_in, const int* in_sizes, int n_in,
                              void* d_out, int out_size, void* d_ws, size_t ws_size,
                              hipStream_t stream) {
    const float* seq  = (const float*)d_in[0];
    const float* kern = (const float*)d_in[1];
    const float* bias = (const float*)d_in[2];
    float* out = (float*)d_out;
    float* ws  = (float*)d_ws;   // B_*TGROUPS*F_*10*4 = 1.31 MB

    dim3 g1(TGROUPS, B_);        // 512 blocks x 512 thr
    ls2t_kernel<<<g1, TPB, 0, stream>>>(seq, kern, bias, ws);
    ls2t_fold_kernel<<<B_, F_, 0, stream>>>(ws, out);
}